// Round 2
// baseline (3918.060 us; speedup 1.0000x reference)
//
#include <hip/hip_runtime.h>

typedef short short8 __attribute__((ext_vector_type(8)));
typedef float f4 __attribute__((ext_vector_type(4)));

#define BATCH 128
#define SEQ   512
#define EMB   256
#define HID   256
#define G4    1024   // 4*HID

static __device__ __forceinline__ unsigned short f2b(float f) {
    union { float f; unsigned int u; } v; v.f = f;
    unsigned int u = v.u;
    return (unsigned short)((u + 0x7FFFu + ((u >> 16) & 1u)) >> 16);  // RNE
}
static __device__ __forceinline__ float b2f(unsigned short s) {
    union { unsigned int u; float f; } v; v.u = ((unsigned int)s) << 16;
    return v.f;
}
static __device__ __forceinline__ float fsig(float x) {
    return 1.0f / (1.0f + __expf(-x));
}
static __device__ __forceinline__ float ftanh(float x) {
    return 2.0f / (1.0f + __expf(-2.0f * x)) - 1.0f;
}

// ---------------- Kernel 0: convert weights to bf16, fold biases ----------------
__global__ void prep_kernel(const float* __restrict__ W_x, const float* __restrict__ U_h,
                            const float* __restrict__ b_x, const float* __restrict__ b_u,
                            const float* __restrict__ b_g,
                            unsigned short* __restrict__ w_xb, unsigned short* __restrict__ u_hb,
                            float* __restrict__ bias) {
    int i = blockIdx.x * blockDim.x + threadIdx.x;
    if (i < G4 * EMB) w_xb[i] = f2b(W_x[i]);
    if (i < G4 * HID) u_hb[i] = f2b(U_h[i]);
    if (i < G4) bias[i] = b_x[i] + b_u[i] + b_g[i];
}

// ---------------- Kernel 1: xp[m][g] = emb[tokens[m]] @ W_x^T + bias (bf16 out) --
__global__ __launch_bounds__(256, 4) void xp_gemm(
    const int* __restrict__ tokens, const float* __restrict__ emb,
    const unsigned short* __restrict__ w_xb, const float* __restrict__ bias,
    unsigned short* __restrict__ xp)
{
    __shared__ unsigned short As[64][264];
    const int m0 = blockIdx.x * 64;
    const int tid = threadIdx.x;
    {
        const int r = tid >> 2, q = tid & 3;
        const int tok = tokens[m0 + r];
        const float* src = emb + (long)tok * EMB + q * 64;
        #pragma unroll
        for (int i = 0; i < 8; ++i) {
            float4 v0 = ((const float4*)src)[2 * i];
            float4 v1 = ((const float4*)src)[2 * i + 1];
            short8 pk;
            pk[0] = (short)f2b(v0.x); pk[1] = (short)f2b(v0.y);
            pk[2] = (short)f2b(v0.z); pk[3] = (short)f2b(v0.w);
            pk[4] = (short)f2b(v1.x); pk[5] = (short)f2b(v1.y);
            pk[6] = (short)f2b(v1.z); pk[7] = (short)f2b(v1.w);
            *(short8*)&As[r][q * 64 + i * 8] = pk;
        }
    }
    __syncthreads();
    const int w = tid >> 6, l = tid & 63;
    const int ln = l & 15, hi = l >> 4;
    short8 a[8];
    #pragma unroll
    for (int kk = 0; kk < 8; ++kk)
        a[kk] = *(const short8*)&As[16 * w + ln][kk * 32 + hi * 8];

    for (int n0 = 0; n0 < G4; n0 += 64) {
        f4 acc[4] = {};
        #pragma unroll
        for (int kk = 0; kk < 8; ++kk) {
            #pragma unroll
            for (int nn = 0; nn < 4; ++nn) {
                short8 b = *(const short8*)&w_xb[(long)(n0 + nn * 16 + ln) * EMB + kk * 32 + hi * 8];
                acc[nn] = __builtin_amdgcn_mfma_f32_16x16x32_bf16(a[kk], b, acc[nn], 0, 0, 0);
            }
        }
        #pragma unroll
        for (int nn = 0; nn < 4; ++nn) {
            const int g = n0 + nn * 16 + ln;
            const float bs = bias[g];
            const int m = m0 + 16 * w + 4 * hi;
            #pragma unroll
            for (int r = 0; r < 4; ++r)
                xp[(long)(m + r) * G4 + g] = f2b(acc[nn][r] + bs);
        }
    }
}

// ---------------- Kernel 2: 512-step LSTM recurrence, 8 blocks x 16 rows --------
// Wave w owns hidden units [32w,32w+32): 8 N-frags = {f,i,c,o} x 2 sub-blocks.
// U_h^T residency: kk0-5 in VGPRs (192 regs), kk6-7 in LDS (128 KB). Nothing streamed.
__global__ __launch_bounds__(512, 1) void lstm_recur(
    const unsigned short* __restrict__ xp,
    const unsigned short* __restrict__ u_hb,
    const float* __restrict__ fc_w, const float* __restrict__ fc_b,
    float* __restrict__ out)
{
    extern __shared__ char smem[];
    unsigned short* Blds = (unsigned short*)smem;             // [2][8][8][64*8] = 128 KB
    unsigned short* hb   = (unsigned short*)(smem + 131072);  // [2][16][264] bf16 = 16896 B
    float* hf32 = (float*)smem;                               // epilogue reuse of Blds (16 KB)
    const int tid = threadIdx.x;
    const int w = tid >> 6, l = tid & 63;
    const int ln = l & 15, hi = l >> 4;
    const int b0 = blockIdx.x * 16;

    int col0[8];
    #pragma unroll
    for (int nn = 0; nn < 8; ++nn)
        col0[nn] = (nn >> 1) * HID + w * 32 + (nn & 1) * 16;

    // preload B regs kk 0..5 (192 VGPRs)
    short8 Br[6][8];
    #pragma unroll
    for (int kk = 0; kk < 6; ++kk)
        #pragma unroll
        for (int nn = 0; nn < 8; ++nn)
            Br[kk][nn] = *(const short8*)&u_hb[(long)(col0[nn] + ln) * HID + kk * 32 + hi * 8];

    // fill B LDS kk 6..7 (each lane fills its own future-read slot)
    #pragma unroll
    for (int kkL = 0; kkL < 2; ++kkL)
        #pragma unroll
        for (int nn = 0; nn < 8; ++nn) {
            short8 v = *(const short8*)&u_hb[(long)(col0[nn] + ln) * HID + (6 + kkL) * 32 + hi * 8];
            *(short8*)&Blds[(size_t)(((kkL * 8 + w) * 8 + nn) * 64 + l) * 8] = v;
        }

    for (int i = tid; i < 2 * 16 * 264; i += 512) hb[i] = 0;
    __syncthreads();

    float c[2][4] = {};

    for (int t = 0; t < SEQ; ++t) {
        const unsigned short* hr = (t & 1) ? (hb + 16 * 264) : hb;
        unsigned short* hw       = (t & 1) ? hb : (hb + 16 * 264);

        // xp for this step: issued first, consumed after all MFMAs -> latency hidden
        unsigned short xv[8][4];
        #pragma unroll
        for (int nn = 0; nn < 8; ++nn)
            #pragma unroll
            for (int r = 0; r < 4; ++r)
                xv[nn][r] = xp[((long)(b0 + 4 * hi + r) * SEQ + t) * G4 + col0[nn] + ln];

        // A frags (h from LDS)
        short8 a[8];
        #pragma unroll
        for (int kk = 0; kk < 8; ++kk)
            a[kk] = *(const short8*)&hr[ln * 264 + kk * 32 + hi * 8];

        f4 acc[8] = {};
        #pragma unroll
        for (int kk = 0; kk < 6; ++kk)
            #pragma unroll
            for (int nn = 0; nn < 8; ++nn)
                acc[nn] = __builtin_amdgcn_mfma_f32_16x16x32_bf16(a[kk], Br[kk][nn], acc[nn], 0, 0, 0);
        #pragma unroll
        for (int kkL = 0; kkL < 2; ++kkL) {
            #pragma unroll
            for (int nn = 0; nn < 8; ++nn) {
                short8 b = *(const short8*)&Blds[(size_t)(((kkL * 8 + w) * 8 + nn) * 64 + l) * 8];
                acc[nn] = __builtin_amdgcn_mfma_f32_16x16x32_bf16(a[6 + kkL], b, acc[nn], 0, 0, 0);
            }
        }

        if (t == SEQ - 1) __syncthreads();  // all Blds reads done -> hf32 may alias Blds

        // gates fully in registers; acc[f]=0..1, acc[i]=2..3, acc[c]=4..5, acc[o]=6..7
        #pragma unroll
        for (int q = 0; q < 2; ++q) {
            #pragma unroll
            for (int r = 0; r < 4; ++r) {
                float gf = acc[0 + q][r] + b2f(xv[0 + q][r]);
                float gi = acc[2 + q][r] + b2f(xv[2 + q][r]);
                float gc = acc[4 + q][r] + b2f(xv[4 + q][r]);
                float go = acc[6 + q][r] + b2f(xv[6 + q][r]);
                float cn = fsig(gf) * c[q][r] + fsig(gi) * ftanh(gc);
                c[q][r] = cn;
                float h = fsig(go) * ftanh(cn);
                hw[(4 * hi + r) * 264 + w * 32 + q * 16 + ln] = f2b(h);
                if (t == SEQ - 1)
                    hf32[(4 * hi + r) * 256 + w * 32 + q * 16 + ln] = h;
            }
        }
        __syncthreads();
    }

    // epilogue: out = h_T @ fc_w^T + fc_b for this block's 16 rows
    if (tid < 32) {
        const int r = tid >> 1, o = tid & 1;
        float s = fc_b[o];
        for (int j = 0; j < HID; ++j)
            s += hf32[r * 256 + j] * fc_w[o * HID + j];
        out[(b0 + r) * 2 + o] = s;
    }
}

extern "C" void kernel_launch(void* const* d_in, const int* in_sizes, int n_in,
                              void* d_out, int out_size, void* d_ws, size_t ws_size,
                              hipStream_t stream) {
    const int*   tokens = (const int*)  d_in[0];
    const float* emb    = (const float*)d_in[1];
    const float* W_x    = (const float*)d_in[2];
    const float* b_x    = (const float*)d_in[3];
    const float* U_h    = (const float*)d_in[4];
    const float* b_u    = (const float*)d_in[5];
    const float* b_g    = (const float*)d_in[6];
    const float* fc_w   = (const float*)d_in[7];
    const float* fc_b   = (const float*)d_in[8];
    float* out = (float*)d_out;

    char* ws = (char*)d_ws;
    unsigned short* w_xb = (unsigned short*)(ws);                 // 512 KB
    unsigned short* u_hb = (unsigned short*)(ws + 524288);        // 512 KB
    float*          bias = (float*)(ws + 1048576);                // 4 KB
    unsigned short* xp   = (unsigned short*)(ws + 1052672);       // 128 MB bf16 [B][S][4H]

    prep_kernel<<<1024, 256, 0, stream>>>(W_x, U_h, b_x, b_u, b_g, w_xb, u_hb, bias);
    xp_gemm<<<1024, 256, 0, stream>>>(tokens, emb, w_xb, bias, xp);

    (void)hipFuncSetAttribute((const void*)lstm_recur,
                              hipFuncAttributeMaxDynamicSharedMemorySize, 147968);
    lstm_recur<<<8, 512, 147968, stream>>>(xp, u_hb, fc_w, fc_b, out);
}

// Round 3
// 2559.173 us; speedup vs baseline: 1.5310x; 1.5310x over previous
//
#include <hip/hip_runtime.h>

typedef short short8 __attribute__((ext_vector_type(8)));
typedef float f4 __attribute__((ext_vector_type(4)));

#define BATCH 128
#define SEQ   512
#define EMB   256
#define HID   256
#define G4    1024   // 4*HID

static __device__ __forceinline__ unsigned short f2b(float f) {
    union { float f; unsigned int u; } v; v.f = f;
    unsigned int u = v.u;
    return (unsigned short)((u + 0x7FFFu + ((u >> 16) & 1u)) >> 16);  // RNE
}
static __device__ __forceinline__ float b2f(unsigned short s) {
    union { unsigned int u; float f; } v; v.u = ((unsigned int)s) << 16;
    return v.f;
}
static __device__ __forceinline__ float fsig(float x) {
    return 1.0f / (1.0f + __expf(-x));
}
static __device__ __forceinline__ float ftanh(float x) {
    return 2.0f / (1.0f + __expf(-2.0f * x)) - 1.0f;
}

// ---------------- Kernel 0: convert weights to bf16, fold biases ----------------
__global__ void prep_kernel(const float* __restrict__ W_x, const float* __restrict__ U_h,
                            const float* __restrict__ b_x, const float* __restrict__ b_u,
                            const float* __restrict__ b_g,
                            unsigned short* __restrict__ w_xb, unsigned short* __restrict__ u_hb,
                            float* __restrict__ bias) {
    int i = blockIdx.x * blockDim.x + threadIdx.x;
    if (i < G4 * EMB) w_xb[i] = f2b(W_x[i]);
    if (i < G4 * HID) u_hb[i] = f2b(U_h[i]);
    if (i < G4) bias[i] = b_x[i] + b_u[i] + b_g[i];
}

// ---------------- Kernel 1: xp[s][b][g] = emb[tokens[b,s]] @ W_x^T + bias --------
// m = b*SEQ + s; tile = 64 consecutive m (same b). Output layout [S][B][G4] bf16.
__global__ __launch_bounds__(256, 4) void xp_gemm(
    const int* __restrict__ tokens, const float* __restrict__ emb,
    const unsigned short* __restrict__ w_xb, const float* __restrict__ bias,
    unsigned short* __restrict__ xp)
{
    __shared__ unsigned short As[64][264];
    const int m0 = blockIdx.x * 64;
    const int b  = m0 >> 9;          // m0 / SEQ
    const int s0 = m0 & 511;         // m0 % SEQ
    const int tid = threadIdx.x;
    {
        const int r = tid >> 2, q = tid & 3;
        const int tok = tokens[m0 + r];
        const float* src = emb + (long)tok * EMB + q * 64;
        #pragma unroll
        for (int i = 0; i < 8; ++i) {
            float4 v0 = ((const float4*)src)[2 * i];
            float4 v1 = ((const float4*)src)[2 * i + 1];
            short8 pk;
            pk[0] = (short)f2b(v0.x); pk[1] = (short)f2b(v0.y);
            pk[2] = (short)f2b(v0.z); pk[3] = (short)f2b(v0.w);
            pk[4] = (short)f2b(v1.x); pk[5] = (short)f2b(v1.y);
            pk[6] = (short)f2b(v1.z); pk[7] = (short)f2b(v1.w);
            *(short8*)&As[r][q * 64 + i * 8] = pk;
        }
    }
    __syncthreads();
    const int w = tid >> 6, l = tid & 63;
    const int ln = l & 15, hi = l >> 4;
    short8 a[8];
    #pragma unroll
    for (int kk = 0; kk < 8; ++kk)
        a[kk] = *(const short8*)&As[16 * w + ln][kk * 32 + hi * 8];

    for (int n0 = 0; n0 < G4; n0 += 64) {
        f4 acc[4] = {};
        #pragma unroll
        for (int kk = 0; kk < 8; ++kk) {
            #pragma unroll
            for (int nn = 0; nn < 4; ++nn) {
                short8 bfr = *(const short8*)&w_xb[(long)(n0 + nn * 16 + ln) * EMB + kk * 32 + hi * 8];
                acc[nn] = __builtin_amdgcn_mfma_f32_16x16x32_bf16(a[kk], bfr, acc[nn], 0, 0, 0);
            }
        }
        #pragma unroll
        for (int nn = 0; nn < 4; ++nn) {
            const int g = n0 + nn * 16 + ln;
            const float bs = bias[g];
            #pragma unroll
            for (int r = 0; r < 4; ++r) {
                const int s = s0 + 16 * w + 4 * hi + r;
                xp[((size_t)s * BATCH + b) * G4 + g] = f2b(acc[nn][r] + bs);
            }
        }
    }
}

// ---------------- Kernel 2: 512-step LSTM recurrence, 8 blocks x 16 rows --------
// Wave w owns hidden units [32w,32w+32): 8 N-frags = {f,i,c,o} x 2 sub-blocks.
// U_h^T residency: kk0-5 in VGPRs (192 regs), kk6-7 in LDS (128 KB).
// acc is initialized from xp (input projection = MFMA C-init): no xv regs.
// Register budget (must fit 256 @ 2 waves/SIMD): Br 192 + acc 32 + av 16 + ~10.
__global__ void __launch_bounds__(512) __attribute__((amdgpu_waves_per_eu(2, 2)))
lstm_recur(const unsigned short* __restrict__ xp,
           const unsigned short* __restrict__ u_hb,
           const float* __restrict__ fc_w, const float* __restrict__ fc_b,
           float* __restrict__ out)
{
    extern __shared__ char smem[];
    unsigned short* Blds = (unsigned short*)smem;             // [2][8][8][64*8] = 128 KB
    unsigned short* hb   = (unsigned short*)(smem + 131072);  // [2][16][264] bf16 = 16896 B
    float* hf32 = (float*)smem;                               // epilogue reuse of Blds (16 KB)
    const int tid = threadIdx.x;
    const int w = tid >> 6, l = tid & 63;
    const int ln = l & 15, hi = l >> 4;
    const int b0 = blockIdx.x * 16;

    // preload B regs kk 0..5 (192 VGPRs)
    short8 Br[6][8];
    #pragma unroll
    for (int kk = 0; kk < 6; ++kk)
        #pragma unroll
        for (int nn = 0; nn < 8; ++nn) {
            const int col = (nn >> 1) * HID + w * 32 + (nn & 1) * 16 + ln;
            Br[kk][nn] = *(const short8*)&u_hb[(long)col * HID + kk * 32 + hi * 8];
        }

    // fill B LDS kk 6..7 (each lane fills its own future-read slot)
    #pragma unroll
    for (int kkL = 0; kkL < 2; ++kkL)
        #pragma unroll
        for (int nn = 0; nn < 8; ++nn) {
            const int col = (nn >> 1) * HID + w * 32 + (nn & 1) * 16 + ln;
            short8 v = *(const short8*)&u_hb[(long)col * HID + (6 + kkL) * 32 + hi * 8];
            *(short8*)&Blds[(size_t)(((kkL * 8 + w) * 8 + nn) * 64 + l) * 8] = v;
        }

    for (int i = tid; i < 2 * 16 * 264; i += 512) hb[i] = 0;
    __syncthreads();

    float c[2][4] = {};

    // per-lane xp bases, layout [S][B][G4]; advance by BATCH*G4 elems per step.
    // element offset for (nn,r): r*G4 + (nn>>1)*256 + (nn&1)*16  (r in 0..1 per base)
    const unsigned short* p01 = xp + ((size_t)(b0 + 4 * hi)) * G4 + w * 32 + ln;
    const unsigned short* p23 = p01 + 2 * (size_t)G4;

    for (int t = 0; t < SEQ; ++t) {
        const unsigned short* hr = (t & 1) ? (hb + 16 * 264) : hb;
        unsigned short* hw       = (t & 1) ? hb : (hb + 16 * 264);

        // 1) init acc from xp (32 x 2-B loads, imm-offset folded; issued first)
        f4 acc[8];
        #pragma unroll
        for (int nn = 0; nn < 8; ++nn) {
            const int co = (nn >> 1) * 256 + (nn & 1) * 16;
            acc[nn][0] = b2f(p01[co]);
            acc[nn][1] = b2f(p01[co + G4]);
            acc[nn][2] = b2f(p23[co]);
            acc[nn][3] = b2f(p23[co + G4]);
        }
        p01 += (size_t)BATCH * G4;
        p23 += (size_t)BATCH * G4;

        // 2) MFMA over K: kk0-3 (regs), then kk4-5 (regs), kk6-7 (LDS), reusing av
        short8 av[4];
        #pragma unroll
        for (int kk = 0; kk < 4; ++kk)
            av[kk] = *(const short8*)&hr[ln * 264 + kk * 32 + hi * 8];
        #pragma unroll
        for (int kk = 0; kk < 4; ++kk)
            #pragma unroll
            for (int nn = 0; nn < 8; ++nn)
                acc[nn] = __builtin_amdgcn_mfma_f32_16x16x32_bf16(av[kk], Br[kk][nn], acc[nn], 0, 0, 0);
        #pragma unroll
        for (int kk = 0; kk < 4; ++kk)
            av[kk] = *(const short8*)&hr[ln * 264 + (kk + 4) * 32 + hi * 8];
        #pragma unroll
        for (int kk = 0; kk < 2; ++kk)
            #pragma unroll
            for (int nn = 0; nn < 8; ++nn)
                acc[nn] = __builtin_amdgcn_mfma_f32_16x16x32_bf16(av[kk], Br[4 + kk][nn], acc[nn], 0, 0, 0);
        #pragma unroll
        for (int kkL = 0; kkL < 2; ++kkL)
            #pragma unroll
            for (int nn = 0; nn < 8; ++nn) {
                short8 bfr = *(const short8*)&Blds[(size_t)(((kkL * 8 + w) * 8 + nn) * 64 + l) * 8];
                acc[nn] = __builtin_amdgcn_mfma_f32_16x16x32_bf16(av[2 + kkL], bfr, acc[nn], 0, 0, 0);
            }

        if (t == SEQ - 1) __syncthreads();  // all Blds reads done -> hf32 may alias Blds

        // 3) gates in registers; acc[f]=0..1, acc[i]=2..3, acc[c]=4..5, acc[o]=6..7
        #pragma unroll
        for (int q = 0; q < 2; ++q) {
            #pragma unroll
            for (int r = 0; r < 4; ++r) {
                float gf = acc[0 + q][r];
                float gi = acc[2 + q][r];
                float gc = acc[4 + q][r];
                float go = acc[6 + q][r];
                float cn = fsig(gf) * c[q][r] + fsig(gi) * ftanh(gc);
                c[q][r] = cn;
                float h = fsig(go) * ftanh(cn);
                hw[(4 * hi + r) * 264 + w * 32 + q * 16 + ln] = f2b(h);
                if (t == SEQ - 1)
                    hf32[(4 * hi + r) * 256 + w * 32 + q * 16 + ln] = h;
            }
        }
        __syncthreads();
    }

    // epilogue: out = h_T @ fc_w^T + fc_b for this block's 16 rows
    if (tid < 32) {
        const int r = tid >> 1, o = tid & 1;
        float s = fc_b[o];
        for (int j = 0; j < HID; ++j)
            s += hf32[r * 256 + j] * fc_w[o * HID + j];
        out[(b0 + r) * 2 + o] = s;
    }
}

extern "C" void kernel_launch(void* const* d_in, const int* in_sizes, int n_in,
                              void* d_out, int out_size, void* d_ws, size_t ws_size,
                              hipStream_t stream) {
    const int*   tokens = (const int*)  d_in[0];
    const float* emb    = (const float*)d_in[1];
    const float* W_x    = (const float*)d_in[2];
    const float* b_x    = (const float*)d_in[3];
    const float* U_h    = (const float*)d_in[4];
    const float* b_u    = (const float*)d_in[5];
    const float* b_g    = (const float*)d_in[6];
    const float* fc_w   = (const float*)d_in[7];
    const float* fc_b   = (const float*)d_in[8];
    float* out = (float*)d_out;

    char* ws = (char*)d_ws;
    unsigned short* w_xb = (unsigned short*)(ws);                 // 512 KB
    unsigned short* u_hb = (unsigned short*)(ws + 524288);        // 512 KB
    float*          bias = (float*)(ws + 1048576);                // 4 KB
    unsigned short* xp   = (unsigned short*)(ws + 1052672);       // 128 MB bf16 [S][B][4H]

    prep_kernel<<<1024, 256, 0, stream>>>(W_x, U_h, b_x, b_u, b_g, w_xb, u_hb, bias);
    xp_gemm<<<1024, 256, 0, stream>>>(tokens, emb, w_xb, bias, xp);

    (void)hipFuncSetAttribute((const void*)lstm_recur,
                              hipFuncAttributeMaxDynamicSharedMemorySize, 147968);
    lstm_recur<<<8, 512, 147968, stream>>>(xp, u_hb, fc_w, fc_b, out);
}

// Round 4
// 1900.607 us; speedup vs baseline: 2.0615x; 1.3465x over previous
//
#include <hip/hip_runtime.h>

typedef short short8 __attribute__((ext_vector_type(8)));
typedef float f4 __attribute__((ext_vector_type(4)));

#define BATCH 128
#define SEQ   512
#define EMB   256
#define HID   256
#define G4    1024   // 4*HID

static __device__ __forceinline__ unsigned short f2b(float f) {
    union { float f; unsigned int u; } v; v.f = f;
    unsigned int u = v.u;
    return (unsigned short)((u + 0x7FFFu + ((u >> 16) & 1u)) >> 16);  // RNE
}
static __device__ __forceinline__ float b2f(unsigned short s) {
    union { unsigned int u; float f; } v; v.u = ((unsigned int)s) << 16;
    return v.f;
}

// ---------------- Kernel 0: convert weights to bf16, fold biases ----------------
__global__ void prep_kernel(const float* __restrict__ W_x, const float* __restrict__ U_h,
                            const float* __restrict__ b_x, const float* __restrict__ b_u,
                            const float* __restrict__ b_g,
                            unsigned short* __restrict__ w_xb, unsigned short* __restrict__ u_hb,
                            float* __restrict__ bias) {
    int i = blockIdx.x * blockDim.x + threadIdx.x;
    if (i < G4 * EMB) w_xb[i] = f2b(W_x[i]);
    if (i < G4 * HID) u_hb[i] = f2b(U_h[i]);
    if (i < G4) bias[i] = b_x[i] + b_u[i] + b_g[i];
}

// ---------------- Kernel 1: xp[s][b][g] = emb[tokens[b,s]] @ W_x^T + bias --------
// m = b*SEQ + s; tile = 64 consecutive m (same b). Output layout [S][B][G4] bf16.
__global__ __launch_bounds__(256, 3) void xp_gemm(
    const int* __restrict__ tokens, const float* __restrict__ emb,
    const unsigned short* __restrict__ w_xb, const float* __restrict__ bias,
    unsigned short* __restrict__ xp)
{
    __shared__ unsigned short As[64][264];   // A tile (33.8 KB)
    __shared__ unsigned short Xs[64][72];    // store-transpose bounce (9.2 KB, 144B rows: 16B-aligned)
    const int m0 = blockIdx.x * 64;
    const int b  = m0 >> 9;          // m0 / SEQ
    const int s0 = m0 & 511;         // m0 % SEQ
    const int tid = threadIdx.x;
    {
        const int r = tid >> 2, q = tid & 3;
        const int tok = tokens[m0 + r];
        const float* src = emb + (long)tok * EMB + q * 64;
        #pragma unroll
        for (int i = 0; i < 8; ++i) {
            float4 v0 = ((const float4*)src)[2 * i];
            float4 v1 = ((const float4*)src)[2 * i + 1];
            short8 pk;
            pk[0] = (short)f2b(v0.x); pk[1] = (short)f2b(v0.y);
            pk[2] = (short)f2b(v0.z); pk[3] = (short)f2b(v0.w);
            pk[4] = (short)f2b(v1.x); pk[5] = (short)f2b(v1.y);
            pk[6] = (short)f2b(v1.z); pk[7] = (short)f2b(v1.w);
            *(short8*)&As[r][q * 64 + i * 8] = pk;
        }
    }
    __syncthreads();
    const int w = tid >> 6, l = tid & 63;
    const int ln = l & 15, hi = l >> 4;
    short8 a[8];
    #pragma unroll
    for (int kk = 0; kk < 8; ++kk)
        a[kk] = *(const short8*)&As[16 * w + ln][kk * 32 + hi * 8];

    const int rl = tid >> 2;            // global-store row (own wave's rows)
    const int cl = (tid & 3) * 16;      // global-store col offset in 64-tile

    for (int n0 = 0; n0 < G4; n0 += 64) {
        f4 acc[4] = {};
        #pragma unroll
        for (int kk = 0; kk < 8; ++kk) {
            #pragma unroll
            for (int nn = 0; nn < 4; ++nn) {
                short8 bfr = *(const short8*)&w_xb[(long)(n0 + nn * 16 + ln) * EMB + kk * 32 + hi * 8];
                acc[nn] = __builtin_amdgcn_mfma_f32_16x16x32_bf16(a[kk], bfr, acc[nn], 0, 0, 0);
            }
        }
        // bounce through LDS for coalesced b128 stores (same-wave rows: no barrier)
        #pragma unroll
        for (int nn = 0; nn < 4; ++nn) {
            const float bs = bias[n0 + nn * 16 + ln];
            #pragma unroll
            for (int r = 0; r < 4; ++r)
                Xs[16 * w + 4 * hi + r][nn * 16 + ln] = f2b(acc[nn][r] + bs);
        }
        size_t off = ((size_t)(s0 + rl) * BATCH + b) * G4 + n0 + cl;
        *(short8*)&xp[off]     = *(const short8*)&Xs[rl][cl];
        *(short8*)&xp[off + 8] = *(const short8*)&Xs[rl][cl + 8];
    }
}

// ---------------- Kernel 2: LSTM recurrence, 32 blocks x 4 rows, 16 waves -------
// Wave w owns hidden units [16w,16w+16); frag g = gate g (f,i,c,o) of those units.
// U_h^T: kk0-5 in VGPRs (96 regs/lane), kk6-7 in LDS (128 KB).
// C rows 0-3 = batch rows (A rows 4-15 read a zero row); gate compaction via shfl
// so each lane computes exactly one (batch,unit) LSTM cell update.
// LDS: Blds 131072 | hb 2x5x264 us @131072 (5280) | xlds 2x4096 us @136352 (16384)
__global__ void __launch_bounds__(1024, 4)
lstm_recur(const unsigned short* __restrict__ xp,
           const unsigned short* __restrict__ u_hb,
           const float* __restrict__ fc_w, const float* __restrict__ fc_b,
           float* __restrict__ out)
{
    extern __shared__ char smem[];
    unsigned short* Blds = (unsigned short*)smem;
    unsigned short* hb   = (unsigned short*)(smem + 131072);
    unsigned short* xlds = (unsigned short*)(smem + 136352);
    const int tid = threadIdx.x;
    const int w = tid >> 6, l = tid & 63;
    const int ln = l & 15, hi = l >> 4;
    const int b0 = blockIdx.x * 4;

    // preload B regs kk 0..5: 6 x 4 frags = 96 VGPRs
    short8 Br[6][4];
    #pragma unroll
    for (int kk = 0; kk < 6; ++kk)
        #pragma unroll
        for (int g = 0; g < 4; ++g) {
            const int col = g * HID + w * 16 + ln;
            Br[kk][g] = *(const short8*)&u_hb[(long)col * HID + kk * 32 + hi * 8];
        }
    // fill B LDS kk 6..7 (lane-private slots)
    #pragma unroll
    for (int kkL = 0; kkL < 2; ++kkL)
        #pragma unroll
        for (int g = 0; g < 4; ++g) {
            const int col = g * HID + w * 16 + ln;
            short8 v = *(const short8*)&u_hb[(long)col * HID + (6 + kkL) * 32 + hi * 8];
            *(short8*)&Blds[(size_t)(kkL * 32768 + w * 2048 + g * 512 + l * 8)] = v;
        }
    // zero h buffers (both, incl. zero-row 4)
    for (int i = tid; i < 2 * 1320; i += 1024) hb[i] = 0;
    // prologue: stage xp tile for t=0 into xlds[0]
    if (w < 8) {
        short8 v = *(const short8*)&xp[(size_t)b0 * G4 + (w * 64 + l) * 8];
        *(short8*)&xlds[(w * 64 + l) * 8] = v;
    }
    __syncthreads();

    const int lnc = (ln < 4) ? ln : 4;          // A rows 4..15 -> shared zero row
    const int hbase = lnc * 264 + hi * 8;       // ushort idx within hb buffer
    const int bb0 = w * 2048 + l * 8;           // Blds kk6 base
    const int bb1 = 32768 + w * 2048 + l * 8;   // Blds kk7 base
    float c = 0.0f;

    for (int t = 0; t < SEQ; ++t) {
        const int cur = t & 1, nxt = cur ^ 1;
        // prefetch next xp tile into regs (consumed at step end)
        short8 sv;
        const bool do_stage = (w < 8) && (t + 1 < SEQ);
        if (do_stage)
            sv = *(const short8*)&xp[((size_t)(t + 1) * BATCH + b0) * G4 + (w * 64 + l) * 8];

        const unsigned short* hr = hb + cur * 1320;
        f4 acc[4] = {};
        short8 a0 = *(const short8*)&hr[hbase];
        short8 a1 = *(const short8*)&hr[hbase + 32];
        #pragma unroll
        for (int g = 0; g < 4; ++g) acc[g] = __builtin_amdgcn_mfma_f32_16x16x32_bf16(a0, Br[0][g], acc[g], 0, 0, 0);
        a0 = *(const short8*)&hr[hbase + 2 * 32];
        #pragma unroll
        for (int g = 0; g < 4; ++g) acc[g] = __builtin_amdgcn_mfma_f32_16x16x32_bf16(a1, Br[1][g], acc[g], 0, 0, 0);
        a1 = *(const short8*)&hr[hbase + 3 * 32];
        #pragma unroll
        for (int g = 0; g < 4; ++g) acc[g] = __builtin_amdgcn_mfma_f32_16x16x32_bf16(a0, Br[2][g], acc[g], 0, 0, 0);
        a0 = *(const short8*)&hr[hbase + 4 * 32];
        #pragma unroll
        for (int g = 0; g < 4; ++g) acc[g] = __builtin_amdgcn_mfma_f32_16x16x32_bf16(a1, Br[3][g], acc[g], 0, 0, 0);
        a1 = *(const short8*)&hr[hbase + 5 * 32];
        #pragma unroll
        for (int g = 0; g < 4; ++g) acc[g] = __builtin_amdgcn_mfma_f32_16x16x32_bf16(a0, Br[4][g], acc[g], 0, 0, 0);
        a0 = *(const short8*)&hr[hbase + 6 * 32];
        #pragma unroll
        for (int g = 0; g < 4; ++g) acc[g] = __builtin_amdgcn_mfma_f32_16x16x32_bf16(a1, Br[5][g], acc[g], 0, 0, 0);
        a1 = *(const short8*)&hr[hbase + 7 * 32];
        #pragma unroll
        for (int g = 0; g < 4; ++g) {
            short8 bl = *(const short8*)&Blds[bb0 + g * 512];
            acc[g] = __builtin_amdgcn_mfma_f32_16x16x32_bf16(a0, bl, acc[g], 0, 0, 0);
        }
        #pragma unroll
        for (int g = 0; g < 4; ++g) {
            short8 bl = *(const short8*)&Blds[bb1 + g * 512];
            acc[g] = __builtin_amdgcn_mfma_f32_16x16x32_bf16(a1, bl, acc[g], 0, 0, 0);
        }

        // gate compaction: lane (ln,hi) <- gates of (batch=hi, unit=16w+ln)
        float val[4];
        #pragma unroll
        for (int g = 0; g < 4; ++g) {
            float t0 = __shfl(acc[g][0], ln);
            float t1 = __shfl(acc[g][1], ln);
            float t2 = __shfl(acc[g][2], ln);
            float t3 = __shfl(acc[g][3], ln);
            float v = (hi == 0) ? t0 : (hi == 1) ? t1 : (hi == 2) ? t2 : t3;
            val[g] = v + b2f(xlds[cur * 4096 + hi * 1024 + g * 256 + w * 16 + ln]);
        }
        // LSTM cell, 8 transcendentals (5 exp + 3 rcp)
        float ea = __expf(-val[0]);            // f-gate
        float ei = __expf(-val[1]);            // i-gate
        float eb = __expf(-2.0f * val[2]);     // tanh(c_hat)
        float eo = __expf(-val[3]);            // o-gate
        float rf = __builtin_amdgcn_rcpf(1.0f + ea);
        float it = (1.0f - eb) * __builtin_amdgcn_rcpf((1.0f + ei) * (1.0f + eb));
        float cn = fmaf(rf, c, it);
        c = cn;
        float ed = __expf(-2.0f * cn);         // tanh(c)
        float h = (1.0f - ed) * __builtin_amdgcn_rcpf((1.0f + eo) * (1.0f + ed));

        hb[nxt * 1320 + hi * 264 + w * 16 + ln] = f2b(h);
        if (t == SEQ - 1)
            ((float*)xlds)[hi * 256 + w * 16 + ln] = h;   // xlds[0] free (no stage at t=511; cur=1)
        if (do_stage)
            *(short8*)&xlds[nxt * 4096 + (w * 64 + l) * 8] = sv;
        __syncthreads();
    }

    // epilogue: out[b0+r][o] = fc_b[o] + sum_j h[r][j]*fc_w[o][j]
    if (tid < 64) {
        const float* hf32 = (const float*)xlds;
        const int r = tid >> 4, o = (tid >> 3) & 1, j0 = tid & 7;
        float s = 0.0f;
        for (int j = j0; j < HID; j += 8)
            s += hf32[r * 256 + j] * fc_w[o * HID + j];
        s += __shfl_down(s, 4);
        s += __shfl_down(s, 2);
        s += __shfl_down(s, 1);
        if (j0 == 0) out[(b0 + r) * 2 + o] = fc_b[o] + s;
    }
}

extern "C" void kernel_launch(void* const* d_in, const int* in_sizes, int n_in,
                              void* d_out, int out_size, void* d_ws, size_t ws_size,
                              hipStream_t stream) {
    const int*   tokens = (const int*)  d_in[0];
    const float* emb    = (const float*)d_in[1];
    const float* W_x    = (const float*)d_in[2];
    const float* b_x    = (const float*)d_in[3];
    const float* U_h    = (const float*)d_in[4];
    const float* b_u    = (const float*)d_in[5];
    const float* b_g    = (const float*)d_in[6];
    const float* fc_w   = (const float*)d_in[7];
    const float* fc_b   = (const float*)d_in[8];
    float* out = (float*)d_out;

    char* ws = (char*)d_ws;
    unsigned short* w_xb = (unsigned short*)(ws);                 // 512 KB
    unsigned short* u_hb = (unsigned short*)(ws + 524288);        // 512 KB
    float*          bias = (float*)(ws + 1048576);                // 4 KB
    unsigned short* xp   = (unsigned short*)(ws + 1052672);       // 128 MB bf16 [S][B][4H]

    prep_kernel<<<1024, 256, 0, stream>>>(W_x, U_h, b_x, b_u, b_g, w_xb, u_hb, bias);
    xp_gemm<<<1024, 256, 0, stream>>>(tokens, emb, w_xb, bias, xp);

    (void)hipFuncSetAttribute((const void*)lstm_recur,
                              hipFuncAttributeMaxDynamicSharedMemorySize, 152736);
    lstm_recur<<<32, 1024, 152736, stream>>>(xp, u_hb, fc_w, fc_b, out);
}